// Round 2
// baseline (3750.011 us; speedup 1.0000x reference)
//
#include <hip/hip_runtime.h>

#define HID 64
#define LL 16
#define NLAYERS 4
#define NN 50000
#define NE 200000
#define PRR 1600000
#define DDIM 100000   // PRR / LL

__device__ __forceinline__ unsigned short f2bf(float x) {
    unsigned u = __float_as_uint(x);
    unsigned r = (u + 0x7fffu + ((u >> 16) & 1u)) >> 16;
    return (unsigned short)r;
}
__device__ __forceinline__ float bf2f(unsigned short v) {
    return __uint_as_float((unsigned)v << 16);
}

// ---------------- h init: h[n,c] = atom_emb[node_feat[n], c] ----------------
__global__ void k_init_h(const int* __restrict__ node_feat,
                         const float* __restrict__ atom_emb,
                         float* __restrict__ h) {
    int t = blockIdx.x * blockDim.x + threadIdx.x;
    if (t >= NN * HID) return;
    int n = t >> 6, c = t & 63;
    h[t] = atom_emb[node_feat[n] * HID + c];
}

// ---- wt[a*4096 + b*64 + c] = w_i[(b*64+c)*16 + a]  ([a][b][c] layout) ------
__global__ void k_transpose_wt(const float* __restrict__ w_i,
                               float* __restrict__ wt) {
    int t = blockIdx.x * blockDim.x + threadIdx.x;   // 65536
    if (t >= LL * HID * HID) return;
    int c = t & 63, b = (t >> 6) & 63, a = t >> 12;
    wt[t] = w_i[(b * HID + c) * LL + a];
}

// ---- ge[(ty*16+a)*64+c] = sum_b bond_emb_i[ty*64+b] * wt[a*4096+b*64+c] ----
__global__ void k_ge(const float* __restrict__ bond_emb_i,
                     const float* __restrict__ wt,
                     float* __restrict__ ge) {
    int t = blockIdx.x * blockDim.x + threadIdx.x;   // 4096
    if (t >= 4 * LL * HID) return;
    int c = t & 63, a = (t >> 6) & 15, ty = t >> 10;
    float s = 0.f;
    for (int b = 0; b < HID; ++b)
        s += bond_emb_i[ty * HID + b] * wt[a * 4096 + b * HID + c];
    ge[t] = s;
}

// ---- g[(n*16+a)*64+c] = sum_b h[n,b] * wt[a][b][c]   (bf16 output) ---------
__global__ void __launch_bounds__(256) k_gemm_g(const float* __restrict__ h,
                                                const float* __restrict__ wt,
                                                unsigned short* __restrict__ g) {
    __shared__ float hs[16 * 64];   // 4 KiB  [node][b]
    __shared__ float ws[64 * 64];   // 16 KiB [b][c], one a-slice
    int tid = threadIdx.x;
    int nbase = blockIdx.x * 16;
    #pragma unroll
    for (int r = 0; r < 4; ++r) {
        int idx = r * 256 + tid;
        hs[idx] = h[(size_t)nbase * HID + idx];
    }
    int c = tid & 63, qd = tid >> 6;
    for (int a = 0; a < LL; ++a) {
        __syncthreads();
        #pragma unroll
        for (int r = 0; r < 16; ++r)
            ws[r * 256 + tid] = wt[a * 4096 + r * 256 + tid];
        __syncthreads();
        float a0 = 0.f, a1 = 0.f, a2 = 0.f, a3 = 0.f;
        #pragma unroll 8
        for (int b = 0; b < 64; ++b) {
            float wv = ws[b * 64 + c];
            a0 += hs[(qd + 0)  * 64 + b] * wv;
            a1 += hs[(qd + 4)  * 64 + b] * wv;
            a2 += hs[(qd + 8)  * 64 + b] * wv;
            a3 += hs[(qd + 12) * 64 + b] * wv;
        }
        g[((size_t)(nbase + qd + 0)  * LL + a) * HID + c] = f2bf(a0);
        g[((size_t)(nbase + qd + 4)  * LL + a) * HID + c] = f2bf(a1);
        g[((size_t)(nbase + qd + 8)  * LL + a) * HID + c] = f2bf(a2);
        g[((size_t)(nbase + qd + 12) * LL + a) * HID + c] = f2bf(a3);
    }
}

// ---- q init: q[d,c] = bias[c] ----------------------------------------------
__global__ void k_fill_q_bias(float* __restrict__ q, const float* __restrict__ bias_i) {
    int t = blockIdx.x * blockDim.x + threadIdx.x;   // DDIM*64
    if (t >= DDIM * HID) return;
    q[t] = bias_i[t & 63];
}

// ---- zero fill --------------------------------------------------------------
__global__ void k_zero(float* __restrict__ buf, int n) {
    int t = blockIdx.x * blockDim.x + threadIdx.x;
    if (t < n) buf[t] = 0.f;
}

// ---- n2p scatter: q[d(r),c] += val * g[(col*16+a(r))*64+c] -------------------
__global__ void k_scatter_n2p(const int* __restrict__ rows,
                              const int* __restrict__ cols,
                              const float* __restrict__ vals,
                              const unsigned short* __restrict__ g,
                              float* __restrict__ q) {
    unsigned t = blockIdx.x * blockDim.x + threadIdx.x;   // PRR*64
    int k = (int)(t >> 6), c = (int)(t & 63);
    int r = rows[k];
    int d = r >> 4, a = r & 15;
    int col = cols[k];
    float gv = bf2f(g[((size_t)col * LL + a) * HID + c]);
    atomicAdd(&q[(size_t)d * HID + c], vals[k] * gv);
}

// ---- e2p scatter: q[d(r),c] += val * ge[(ef*16+a(r))*64+c] -------------------
__global__ void k_scatter_e2p(const int* __restrict__ rows,
                              const int* __restrict__ cols,
                              const float* __restrict__ vals,
                              const int* __restrict__ edge_feat,
                              const float* __restrict__ ge,
                              float* __restrict__ q) {
    unsigned t = blockIdx.x * blockDim.x + threadIdx.x;   // (PRR/2)*64
    int k = (int)(t >> 6), c = (int)(t & 63);
    int r = rows[k];
    int d = r >> 4, a = r & 15;
    int ef = edge_feat[cols[k]];
    atomicAdd(&q[(size_t)d * HID + c], vals[k] * ge[(ef * LL + a) * HID + c]);
}

// ---- pool: pn[pr[k],c] += pv[k] * relu(q[pc[k],c]) ---------------------------
__global__ void k_pool(const int* __restrict__ rows,
                       const int* __restrict__ cols,
                       const float* __restrict__ vals,
                       const float* __restrict__ q,
                       float* __restrict__ pn) {
    unsigned t = blockIdx.x * blockDim.x + threadIdx.x;   // DDIM*64
    int k = (int)(t >> 6), c = (int)(t & 63);
    float qv = fmaxf(q[(size_t)cols[k] * HID + c], 0.f);
    atomicAdd(&pn[(size_t)rows[k] * HID + c], vals[k] * qv);
}

// ---- gate: h[n,c] = pn[n,c] * (d1b[c] + sum_j d1w[c,j]*relu(deg*d0w[j]+d0b[j]))
__global__ void k_gate(const float* __restrict__ degs,
                       const float* __restrict__ d0w,   // [128]
                       const float* __restrict__ d0b,   // [128]
                       const float* __restrict__ d1w,   // [64,128]
                       const float* __restrict__ d1b,   // [64]
                       const float* __restrict__ pn,
                       float* __restrict__ h) {
    int t = blockIdx.x * blockDim.x + threadIdx.x;        // NN*64
    if (t >= NN * HID) return;
    int n = t >> 6, c = t & 63;
    float deg = degs[n];
    float rv0 = fmaxf(deg * d0w[c]      + d0b[c],      0.f);
    float rv1 = fmaxf(deg * d0w[64 + c] + d0b[64 + c], 0.f);
    float acc = d1b[c];
    #pragma unroll 8
    for (int j = 0; j < 64; ++j) {
        float f0 = __shfl(rv0, j, 64);
        float f1 = __shfl(rv1, j, 64);
        acc += d1w[c * 128 + j]      * f0;
        acc += d1w[c * 128 + 64 + j] * f1;
    }
    h[t] = pn[t] * acc;
}

// ---- column-sum reduce ------------------------------------------------------
__global__ void k_reduce(const float* __restrict__ h, float* __restrict__ acc) {
    __shared__ float lds[256];
    int tid = threadIdx.x;
    float s = 0.f;
    for (int idx = blockIdx.x * 256 + tid; idx < NN * HID; idx += gridDim.x * 256)
        s += h[idx];
    lds[tid] = s;
    __syncthreads();
    if (tid < 64) {
        s = lds[tid] + lds[tid + 64] + lds[tid + 128] + lds[tid + 192];
        atomicAdd(&acc[tid], s);
    }
}

__global__ void k_final(const float* __restrict__ acc,
                        const float* __restrict__ fw,
                        const float* __restrict__ fb,
                        float* __restrict__ out) {
    int lane = threadIdx.x;   // 64 threads
    float v = acc[lane] * (1.0f / NN) * fw[lane];
    for (int off = 32; off; off >>= 1) v += __shfl_down(v, off, 64);
    if (lane == 0) out[0] = v + fb[0];
}

extern "C" void kernel_launch(void* const* d_in, const int* in_sizes, int n_in,
                              void* d_out, int out_size, void* d_ws, size_t ws_size,
                              hipStream_t stream) {
    const int*   node_feat = (const int*)d_in[0];
    const int*   edge_feat = (const int*)d_in[1];
    const float* degs      = (const float*)d_in[2];
    const int*   n2p_rows  = (const int*)d_in[3];
    const int*   n2p_cols  = (const int*)d_in[4];
    const float* n2p_vals  = (const float*)d_in[5];
    const int*   e2p_rows  = (const int*)d_in[6];
    const int*   e2p_cols  = (const int*)d_in[7];
    const float* e2p_vals  = (const float*)d_in[8];
    const int*   pool_rows = (const int*)d_in[9];
    const int*   pool_cols = (const int*)d_in[10];
    const float* pool_vals = (const float*)d_in[11];
    // d_in[12] = perm_rows scalar (compile-time PRR)
    const float* atom_emb  = (const float*)d_in[13];
    const float* bond_emb  = (const float*)d_in[14];  // [4,4,64]
    const float* weights   = (const float*)d_in[15];  // [4,64,64,16]
    const float* bias      = (const float*)d_in[16];  // [4,64]
    const float* deg0_w    = (const float*)d_in[17];  // [4,128,1]
    const float* deg0_b    = (const float*)d_in[18];  // [4,128]
    const float* deg1_w    = (const float*)d_in[19];  // [4,64,128]
    const float* deg1_b    = (const float*)d_in[20];  // [4,64]
    const float* final_w   = (const float*)d_in[21];  // [1,64]
    const float* final_b   = (const float*)d_in[22];  // [1]
    float* out = (float*)d_out;

    char* wsb = (char*)d_ws;
    size_t off = 0;
    auto alloc = [&](size_t bytes) -> void* {
        void* ptr = wsb + off;
        off += (bytes + 255) & ~(size_t)255;
        return ptr;
    };
    float*          h   = (float*)alloc((size_t)NN * HID * 4);          // 12.8 MB
    unsigned short* g   = (unsigned short*)alloc((size_t)NN * LL * HID * 2); // 102.4 MB
    float*          q   = (float*)alloc((size_t)DDIM * HID * 4);        // 25.6 MB
    float*          pn  = (float*)alloc((size_t)NN * HID * 4);          // 12.8 MB
    float*          wt  = (float*)alloc((size_t)LL * HID * HID * 4);    // 256 KB
    float*          ge  = (float*)alloc((size_t)4 * LL * HID * 4);      // 16 KB
    float*          acc = (float*)alloc(64 * 4);

    k_init_h<<<(NN * HID + 255) / 256, 256, 0, stream>>>(node_feat, atom_emb, h);

    for (int i = 0; i < NLAYERS; ++i) {
        const float* w_i = weights + (size_t)i * HID * HID * LL;
        k_transpose_wt<<<(LL * HID * HID) / 256, 256, 0, stream>>>(w_i, wt);
        k_ge<<<(4 * LL * HID) / 256, 256, 0, stream>>>(bond_emb + i * 4 * HID, wt, ge);
        k_gemm_g<<<NN / 16, 256, 0, stream>>>(h, wt, g);
        k_fill_q_bias<<<(DDIM * HID) / 256, 256, 0, stream>>>(q, bias + i * HID);
        k_scatter_n2p<<<(PRR * HID) / 256, 256, 0, stream>>>(n2p_rows, n2p_cols, n2p_vals, g, q);
        k_scatter_e2p<<<(PRR / 2 * HID) / 256, 256, 0, stream>>>(e2p_rows, e2p_cols, e2p_vals,
                                                                 edge_feat, ge, q);
        k_zero<<<(NN * HID + 255) / 256, 256, 0, stream>>>(pn, NN * HID);
        k_pool<<<(DDIM * HID) / 256, 256, 0, stream>>>(pool_rows, pool_cols, pool_vals, q, pn);
        k_gate<<<(NN * HID + 255) / 256, 256, 0, stream>>>(degs,
                                                           deg0_w + i * 2 * HID,
                                                           deg0_b + i * 2 * HID,
                                                           deg1_w + (size_t)i * HID * 2 * HID,
                                                           deg1_b + i * HID,
                                                           pn, h);
    }

    k_zero<<<1, 64, 0, stream>>>(acc, 64);
    k_reduce<<<256, 256, 0, stream>>>(h, acc);
    k_final<<<1, 64, 0, stream>>>(acc, final_w, final_b, out);
}

// Round 3
// 2178.410 us; speedup vs baseline: 1.7214x; 1.7214x over previous
//
#include <hip/hip_runtime.h>

#define HID 64
#define LL 16
#define NLAYERS 4
#define NN 50000
#define NE 200000
#define PRR 1600000
#define DDIM 100000   // PRR / LL

__device__ __forceinline__ unsigned short f2bf(float x) {
    unsigned u = __float_as_uint(x);
    unsigned r = (u + 0x7fffu + ((u >> 16) & 1u)) >> 16;
    return (unsigned short)r;
}
__device__ __forceinline__ float bf2f(unsigned short v) {
    return __uint_as_float((unsigned)v << 16);
}

// ======================= CSR build (once per call) ==========================
__global__ void k_zero_i(int* __restrict__ b, int n) {
    int t = blockIdx.x * blockDim.x + threadIdx.x;
    if (t < n) b[t] = 0;
}
__global__ void k_copy_i(const int* __restrict__ s, int* __restrict__ d, int n) {
    int t = blockIdx.x * blockDim.x + threadIdx.x;
    if (t < n) d[t] = s[t];
}
__global__ void k_set_int(int* __restrict__ p, int v) { *p = v; }

// bin = rows[k] >> shift
__global__ void k_hist(const int* __restrict__ rows, int n, int shift,
                       int* __restrict__ cnt) {
    int k = blockIdx.x * blockDim.x + threadIdx.x;
    if (k >= n) return;
    atomicAdd(&cnt[rows[k] >> shift], 1);
}

// per-block exclusive scan over 1024 elems; partial[b] = block total
__global__ void __launch_bounds__(256) k_scan_block(const int* __restrict__ cnt,
                                                    int* __restrict__ excl,
                                                    int* __restrict__ partial, int B) {
    __shared__ int lds[1024];
    int tid = threadIdx.x;
    int base = blockIdx.x * 1024;
    int self[4];
    #pragma unroll
    for (int r = 0; r < 4; ++r) {
        int i = r * 256 + tid;
        self[r] = (base + i < B) ? cnt[base + i] : 0;
        lds[i] = self[r];
    }
    __syncthreads();
    for (int off = 1; off < 1024; off <<= 1) {
        int v[4];
        #pragma unroll
        for (int r = 0; r < 4; ++r) {
            int i = r * 256 + tid;
            v[r] = (i >= off) ? lds[i - off] : 0;
        }
        __syncthreads();
        #pragma unroll
        for (int r = 0; r < 4; ++r) lds[r * 256 + tid] += v[r];
        __syncthreads();
    }
    #pragma unroll
    for (int r = 0; r < 4; ++r) {
        int i = r * 256 + tid;
        if (base + i < B) excl[base + i] = lds[i] - self[r];
    }
    if (tid == 0) partial[blockIdx.x] = lds[1023];
}

__global__ void k_scan_partial(int* __restrict__ partial, int nb) {
    if (threadIdx.x == 0) {
        int run = 0;
        for (int i = 0; i < nb; ++i) { int v = partial[i]; partial[i] = run; run += v; }
    }
}

__global__ void k_scan_add(int* __restrict__ excl, const int* __restrict__ partial, int B) {
    int i = blockIdx.x * blockDim.x + threadIdx.x;
    if (i < B) excl[i] += partial[i >> 10];
}

// entry = (payload, val_bits)
__global__ void k_fill_n2p(const int* __restrict__ rows, const int* __restrict__ cols,
                           const float* __restrict__ vals, int* __restrict__ cur,
                           uint2* __restrict__ ent) {
    int k = blockIdx.x * blockDim.x + threadIdx.x;
    if (k >= PRR) return;
    int r = rows[k];
    int pos = atomicAdd(&cur[r >> 4], 1);
    ent[pos] = make_uint2(((unsigned)cols[k] << 4) | (unsigned)(r & 15),
                          __float_as_uint(vals[k]));
}
__global__ void k_fill_e2p(const int* __restrict__ rows, const int* __restrict__ cols,
                           const float* __restrict__ vals, const int* __restrict__ ef_arr,
                           int* __restrict__ cur, uint2* __restrict__ ent) {
    int k = blockIdx.x * blockDim.x + threadIdx.x;
    if (k >= PRR / 2) return;
    int r = rows[k];
    int ef = ef_arr[cols[k]];
    int pos = atomicAdd(&cur[r >> 4], 1);
    ent[pos] = make_uint2((unsigned)(ef * LL + (r & 15)), __float_as_uint(vals[k]));
}
__global__ void k_fill_pool(const int* __restrict__ rows, const int* __restrict__ cols,
                            const float* __restrict__ vals, int* __restrict__ cur,
                            uint2* __restrict__ ent) {
    int k = blockIdx.x * blockDim.x + threadIdx.x;
    if (k >= DDIM) return;
    int pos = atomicAdd(&cur[rows[k]], 1);
    ent[pos] = make_uint2((unsigned)cols[k], __float_as_uint(vals[k]));
}

// ============================ per-layer kernels =============================
__global__ void k_init_h(const int* __restrict__ node_feat,
                         const float* __restrict__ atom_emb,
                         float* __restrict__ h) {
    int t = blockIdx.x * blockDim.x + threadIdx.x;
    if (t >= NN * HID) return;
    int n = t >> 6, c = t & 63;
    h[t] = atom_emb[node_feat[n] * HID + c];
}

// wt[a*4096 + b*64 + c] = w_i[(b*64+c)*16 + a]
__global__ void k_transpose_wt(const float* __restrict__ w_i, float* __restrict__ wt) {
    int t = blockIdx.x * blockDim.x + threadIdx.x;
    if (t >= LL * HID * HID) return;
    int c = t & 63, b = (t >> 6) & 63, a = t >> 12;
    wt[t] = w_i[(b * HID + c) * LL + a];
}

// d1wT[j*64+c] = d1w[c*128+j]
__global__ void k_transpose_d1w(const float* __restrict__ d1w, float* __restrict__ d1wT) {
    int t = blockIdx.x * blockDim.x + threadIdx.x;
    if (t >= 128 * HID) return;
    int c = t & 63, j = t >> 6;
    d1wT[t] = d1w[c * 128 + j];
}

// ge[(ty*16+a)*64+c] = sum_b bond_emb_i[ty*64+b] * wt[a*4096+b*64+c]
__global__ void k_ge(const float* __restrict__ bond_emb_i,
                     const float* __restrict__ wt, float* __restrict__ ge) {
    int t = blockIdx.x * blockDim.x + threadIdx.x;
    if (t >= 4 * LL * HID) return;
    int c = t & 63, a = (t >> 6) & 15, ty = t >> 10;
    float s = 0.f;
    for (int b = 0; b < HID; ++b)
        s += bond_emb_i[ty * HID + b] * wt[a * 4096 + b * HID + c];
    ge[t] = s;
}

// g[(n*16+a)*64+c] = sum_b h[n,b] * wt[a][b][c]   (bf16)
__global__ void __launch_bounds__(256) k_gemm_g(const float* __restrict__ h,
                                                const float* __restrict__ wt,
                                                unsigned short* __restrict__ g) {
    __shared__ float hs[16 * 64];
    __shared__ float ws[64 * 64];
    int tid = threadIdx.x;
    int nbase = blockIdx.x * 16;
    #pragma unroll
    for (int r = 0; r < 4; ++r) {
        int idx = r * 256 + tid;
        hs[idx] = h[(size_t)nbase * HID + idx];
    }
    int c = tid & 63, qd = tid >> 6;
    for (int a = 0; a < LL; ++a) {
        __syncthreads();
        #pragma unroll
        for (int r = 0; r < 16; ++r)
            ws[r * 256 + tid] = wt[a * 4096 + r * 256 + tid];
        __syncthreads();
        float a0 = 0.f, a1 = 0.f, a2 = 0.f, a3 = 0.f;
        #pragma unroll 8
        for (int b = 0; b < 64; ++b) {
            float wv = ws[b * 64 + c];
            a0 += hs[(qd + 0)  * 64 + b] * wv;
            a1 += hs[(qd + 4)  * 64 + b] * wv;
            a2 += hs[(qd + 8)  * 64 + b] * wv;
            a3 += hs[(qd + 12) * 64 + b] * wv;
        }
        g[((size_t)(nbase + qd + 0)  * LL + a) * HID + c] = f2bf(a0);
        g[((size_t)(nbase + qd + 4)  * LL + a) * HID + c] = f2bf(a1);
        g[((size_t)(nbase + qd + 8)  * LL + a) * HID + c] = f2bf(a2);
        g[((size_t)(nbase + qd + 12) * LL + a) * HID + c] = f2bf(a3);
    }
}

// fused n2p-gather + e2p-gather + bias + relu: one wave per d
__global__ void __launch_bounds__(256) k_gather_q(
        const int* __restrict__ n2p_start, const uint2* __restrict__ n2p_ent,
        const int* __restrict__ e2p_start, const uint2* __restrict__ e2p_ent,
        const unsigned short* __restrict__ g, const float* __restrict__ ge,
        const float* __restrict__ bias_i, float* __restrict__ qrelu) {
    int wid = (blockIdx.x * 256 + threadIdx.x) >> 6;
    if (wid >= DDIM) return;
    int c = threadIdx.x & 63;
    float acc = bias_i[c];
    int s0 = n2p_start[wid], s1 = n2p_start[wid + 1];
    for (int j = s0; j < s1; ++j) {
        uint2 e = n2p_ent[j];
        acc += __uint_as_float(e.y) * bf2f(g[(size_t)e.x * HID + c]);
    }
    s0 = e2p_start[wid]; s1 = e2p_start[wid + 1];
    for (int j = s0; j < s1; ++j) {
        uint2 e = e2p_ent[j];
        acc += __uint_as_float(e.y) * ge[e.x * HID + c];
    }
    qrelu[(size_t)wid * HID + c] = fmaxf(acc, 0.f);
}

// fused pool-gather + degree gate: one wave per node
__global__ void __launch_bounds__(256) k_pool_gate(
        const int* __restrict__ pstart, const uint2* __restrict__ pent,
        const float* __restrict__ qrelu, const float* __restrict__ degs,
        const float* __restrict__ d0w, const float* __restrict__ d0b,
        const float* __restrict__ d1wT, const float* __restrict__ d1b,
        float* __restrict__ h) {
    int wid = (blockIdx.x * 256 + threadIdx.x) >> 6;
    if (wid >= NN) return;
    int c = threadIdx.x & 63;
    float acc = 0.f;
    int s0 = pstart[wid], s1 = pstart[wid + 1];
    for (int j = s0; j < s1; ++j) {
        uint2 e = pent[j];
        acc += __uint_as_float(e.y) * qrelu[(size_t)e.x * HID + c];
    }
    float deg = degs[wid];
    float rv0 = fmaxf(deg * d0w[c]      + d0b[c],      0.f);
    float rv1 = fmaxf(deg * d0w[64 + c] + d0b[64 + c], 0.f);
    float gf = d1b[c];
    #pragma unroll 8
    for (int j = 0; j < 64; ++j) {
        float f0 = __shfl(rv0, j, 64);
        float f1 = __shfl(rv1, j, 64);
        gf += d1wT[j * HID + c] * f0 + d1wT[(64 + j) * HID + c] * f1;
    }
    h[(size_t)wid * HID + c] = acc * gf;
}

// ============================== epilogue ====================================
__global__ void k_reduce(const float* __restrict__ h, float* __restrict__ acc) {
    __shared__ float lds[256];
    int tid = threadIdx.x;
    float s = 0.f;
    for (int idx = blockIdx.x * 256 + tid; idx < NN * HID; idx += gridDim.x * 256)
        s += h[idx];
    lds[tid] = s;
    __syncthreads();
    if (tid < 64) {
        s = lds[tid] + lds[tid + 64] + lds[tid + 128] + lds[tid + 192];
        atomicAdd(&acc[tid], s);
    }
}

__global__ void k_final(const float* __restrict__ acc, const float* __restrict__ fw,
                        const float* __restrict__ fb, float* __restrict__ out) {
    int lane = threadIdx.x;
    float v = acc[lane] * (1.0f / NN) * fw[lane];
    for (int off = 32; off; off >>= 1) v += __shfl_down(v, off, 64);
    if (lane == 0) out[0] = v + fb[0];
}

// ============================================================================
extern "C" void kernel_launch(void* const* d_in, const int* in_sizes, int n_in,
                              void* d_out, int out_size, void* d_ws, size_t ws_size,
                              hipStream_t stream) {
    const int*   node_feat = (const int*)d_in[0];
    const int*   edge_feat = (const int*)d_in[1];
    const float* degs      = (const float*)d_in[2];
    const int*   n2p_rows  = (const int*)d_in[3];
    const int*   n2p_cols  = (const int*)d_in[4];
    const float* n2p_vals  = (const float*)d_in[5];
    const int*   e2p_rows  = (const int*)d_in[6];
    const int*   e2p_cols  = (const int*)d_in[7];
    const float* e2p_vals  = (const float*)d_in[8];
    const int*   pool_rows = (const int*)d_in[9];
    const int*   pool_cols = (const int*)d_in[10];
    const float* pool_vals = (const float*)d_in[11];
    const float* atom_emb  = (const float*)d_in[13];
    const float* bond_emb  = (const float*)d_in[14];
    const float* weights   = (const float*)d_in[15];
    const float* bias      = (const float*)d_in[16];
    const float* deg0_w    = (const float*)d_in[17];
    const float* deg0_b    = (const float*)d_in[18];
    const float* deg1_w    = (const float*)d_in[19];
    const float* deg1_b    = (const float*)d_in[20];
    const float* final_w   = (const float*)d_in[21];
    const float* final_b   = (const float*)d_in[22];
    float* out = (float*)d_out;

    char* wsb = (char*)d_ws;
    size_t off = 0;
    auto alloc = [&](size_t bytes) -> void* {
        void* ptr = wsb + off;
        off += (bytes + 255) & ~(size_t)255;
        return ptr;
    };
    float*          h       = (float*)alloc((size_t)NN * HID * 4);            // 12.8 MB
    unsigned short* g       = (unsigned short*)alloc((size_t)NN * LL * HID * 2); // 102.4 MB
    float*          qrelu   = (float*)alloc((size_t)DDIM * HID * 4);          // 25.6 MB
    float*          wt      = (float*)alloc((size_t)LL * HID * HID * 4);
    float*          ge      = (float*)alloc((size_t)4 * LL * HID * 4);
    float*          d1wT    = (float*)alloc((size_t)128 * HID * 4);
    float*          acc     = (float*)alloc(64 * 4);
    int*   n2p_start = (int*)alloc((size_t)(DDIM + 1) * 4);
    int*   e2p_start = (int*)alloc((size_t)(DDIM + 1) * 4);
    int*   pool_start= (int*)alloc((size_t)(NN + 1) * 4);
    int*   cursor    = (int*)alloc((size_t)(DDIM + 1) * 4);   // reused sequentially
    int*   partial   = (int*)alloc(512 * 4);
    uint2* n2p_ent   = (uint2*)alloc((size_t)PRR * 8);        // 12.8 MB
    uint2* e2p_ent   = (uint2*)alloc((size_t)(PRR / 2) * 8);  // 6.4 MB
    uint2* pool_ent  = (uint2*)alloc((size_t)DDIM * 8);       // 0.8 MB

    // ---------------- CSR build (shared across layers) ----------------------
    // n2p: bins = DDIM, M = PRR
    k_zero_i<<<(DDIM + 255) / 256, 256, 0, stream>>>(n2p_start, DDIM);
    k_hist<<<(PRR + 255) / 256, 256, 0, stream>>>(n2p_rows, PRR, 4, n2p_start);
    k_scan_block<<<(DDIM + 1023) / 1024, 256, 0, stream>>>(n2p_start, cursor, partial, DDIM);
    k_scan_partial<<<1, 64, 0, stream>>>(partial, (DDIM + 1023) / 1024);
    k_scan_add<<<(DDIM + 255) / 256, 256, 0, stream>>>(cursor, partial, DDIM);
    k_copy_i<<<(DDIM + 255) / 256, 256, 0, stream>>>(cursor, n2p_start, DDIM);
    k_set_int<<<1, 1, 0, stream>>>(n2p_start + DDIM, PRR);
    k_fill_n2p<<<(PRR + 255) / 256, 256, 0, stream>>>(n2p_rows, n2p_cols, n2p_vals, cursor, n2p_ent);

    // e2p: bins = DDIM, M = PRR/2
    k_zero_i<<<(DDIM + 255) / 256, 256, 0, stream>>>(e2p_start, DDIM);
    k_hist<<<(PRR / 2 + 255) / 256, 256, 0, stream>>>(e2p_rows, PRR / 2, 4, e2p_start);
    k_scan_block<<<(DDIM + 1023) / 1024, 256, 0, stream>>>(e2p_start, cursor, partial, DDIM);
    k_scan_partial<<<1, 64, 0, stream>>>(partial, (DDIM + 1023) / 1024);
    k_scan_add<<<(DDIM + 255) / 256, 256, 0, stream>>>(cursor, partial, DDIM);
    k_copy_i<<<(DDIM + 255) / 256, 256, 0, stream>>>(cursor, e2p_start, DDIM);
    k_set_int<<<1, 1, 0, stream>>>(e2p_start + DDIM, PRR / 2);
    k_fill_e2p<<<(PRR / 2 + 255) / 256, 256, 0, stream>>>(e2p_rows, e2p_cols, e2p_vals,
                                                          edge_feat, cursor, e2p_ent);

    // pool: bins = NN, M = DDIM
    k_zero_i<<<(NN + 255) / 256, 256, 0, stream>>>(pool_start, NN);
    k_hist<<<(DDIM + 255) / 256, 256, 0, stream>>>(pool_rows, DDIM, 0, pool_start);
    k_scan_block<<<(NN + 1023) / 1024, 256, 0, stream>>>(pool_start, cursor, partial, NN);
    k_scan_partial<<<1, 64, 0, stream>>>(partial, (NN + 1023) / 1024);
    k_scan_add<<<(NN + 255) / 256, 256, 0, stream>>>(cursor, partial, NN);
    k_copy_i<<<(NN + 255) / 256, 256, 0, stream>>>(cursor, pool_start, NN);
    k_set_int<<<1, 1, 0, stream>>>(pool_start + NN, DDIM);
    k_fill_pool<<<(DDIM + 255) / 256, 256, 0, stream>>>(pool_rows, pool_cols, pool_vals,
                                                        cursor, pool_ent);

    // ---------------- layers ------------------------------------------------
    k_init_h<<<(NN * HID + 255) / 256, 256, 0, stream>>>(node_feat, atom_emb, h);

    for (int i = 0; i < NLAYERS; ++i) {
        const float* w_i = weights + (size_t)i * HID * HID * LL;
        k_transpose_wt<<<(LL * HID * HID) / 256, 256, 0, stream>>>(w_i, wt);
        k_ge<<<(4 * LL * HID) / 256, 256, 0, stream>>>(bond_emb + i * 4 * HID, wt, ge);
        k_transpose_d1w<<<(128 * HID) / 256, 256, 0, stream>>>(deg1_w + (size_t)i * HID * 128, d1wT);
        k_gemm_g<<<NN / 16, 256, 0, stream>>>(h, wt, g);
        k_gather_q<<<(DDIM * HID) / 256, 256, 0, stream>>>(n2p_start, n2p_ent,
                                                           e2p_start, e2p_ent,
                                                           g, ge, bias + i * HID, qrelu);
        k_pool_gate<<<(NN * HID + 255) / 256, 256, 0, stream>>>(pool_start, pool_ent,
                                                                qrelu, degs,
                                                                deg0_w + i * 2 * HID,
                                                                deg0_b + i * 2 * HID,
                                                                d1wT,
                                                                deg1_b + i * HID, h);
    }

    k_zero_i<<<1, 64, 0, stream>>>((int*)acc, 64);
    k_reduce<<<256, 256, 0, stream>>>(h, acc);
    k_final<<<1, 64, 0, stream>>>(acc, final_w, final_b, out);
}

// Round 4
// 1403.848 us; speedup vs baseline: 2.6712x; 1.5517x over previous
//
#include <hip/hip_runtime.h>

#define HID 64
#define LL 16
#define NLAYERS 4
#define NN 50000
#define NE 200000
#define PRR 1600000
#define DDIM 100000   // PRR / LL

typedef __attribute__((ext_vector_type(8))) short bf16x8;
typedef __attribute__((ext_vector_type(4))) float f32x4;

__device__ __forceinline__ unsigned short f2bf(float x) {
    unsigned u = __float_as_uint(x);
    unsigned r = (u + 0x7fffu + ((u >> 16) & 1u)) >> 16;
    return (unsigned short)r;
}
__device__ __forceinline__ float bf2f(unsigned short v) {
    return __uint_as_float((unsigned)v << 16);
}

// ======================= CSR build (once per call) ==========================
__global__ void k_zero_i(int* __restrict__ b, int n) {
    int t = blockIdx.x * blockDim.x + threadIdx.x;
    if (t < n) b[t] = 0;
}
__global__ void k_copy_i(const int* __restrict__ s, int* __restrict__ d, int n) {
    int t = blockIdx.x * blockDim.x + threadIdx.x;
    if (t < n) d[t] = s[t];
}
__global__ void k_set_int(int* __restrict__ p, int v) { *p = v; }

__global__ void k_hist(const int* __restrict__ rows, int n, int shift,
                       int* __restrict__ cnt) {
    int k = blockIdx.x * blockDim.x + threadIdx.x;
    if (k >= n) return;
    atomicAdd(&cnt[rows[k] >> shift], 1);
}

__global__ void __launch_bounds__(256) k_scan_block(const int* __restrict__ cnt,
                                                    int* __restrict__ excl,
                                                    int* __restrict__ partial, int B) {
    __shared__ int lds[1024];
    int tid = threadIdx.x;
    int base = blockIdx.x * 1024;
    int self[4];
    #pragma unroll
    for (int r = 0; r < 4; ++r) {
        int i = r * 256 + tid;
        self[r] = (base + i < B) ? cnt[base + i] : 0;
        lds[i] = self[r];
    }
    __syncthreads();
    for (int off = 1; off < 1024; off <<= 1) {
        int v[4];
        #pragma unroll
        for (int r = 0; r < 4; ++r) {
            int i = r * 256 + tid;
            v[r] = (i >= off) ? lds[i - off] : 0;
        }
        __syncthreads();
        #pragma unroll
        for (int r = 0; r < 4; ++r) lds[r * 256 + tid] += v[r];
        __syncthreads();
    }
    #pragma unroll
    for (int r = 0; r < 4; ++r) {
        int i = r * 256 + tid;
        if (base + i < B) excl[base + i] = lds[i] - self[r];
    }
    if (tid == 0) partial[blockIdx.x] = lds[1023];
}

__global__ void k_scan_partial(int* __restrict__ partial, int nb) {
    if (threadIdx.x == 0) {
        int run = 0;
        for (int i = 0; i < nb; ++i) { int v = partial[i]; partial[i] = run; run += v; }
    }
}

__global__ void k_scan_add(int* __restrict__ excl, const int* __restrict__ partial, int B) {
    int i = blockIdx.x * blockDim.x + threadIdx.x;
    if (i < B) excl[i] += partial[i >> 10];
}

__global__ void k_fill_n2p(const int* __restrict__ rows, const int* __restrict__ cols,
                           const float* __restrict__ vals, int* __restrict__ cur,
                           uint2* __restrict__ ent) {
    int k = blockIdx.x * blockDim.x + threadIdx.x;
    if (k >= PRR) return;
    int r = rows[k];
    int pos = atomicAdd(&cur[r >> 4], 1);
    ent[pos] = make_uint2(((unsigned)cols[k] << 4) | (unsigned)(r & 15),
                          __float_as_uint(vals[k]));
}
__global__ void k_fill_e2p(const int* __restrict__ rows, const int* __restrict__ cols,
                           const float* __restrict__ vals, const int* __restrict__ ef_arr,
                           int* __restrict__ cur, uint2* __restrict__ ent) {
    int k = blockIdx.x * blockDim.x + threadIdx.x;
    if (k >= PRR / 2) return;
    int r = rows[k];
    int ef = ef_arr[cols[k]];
    int pos = atomicAdd(&cur[r >> 4], 1);
    ent[pos] = make_uint2((unsigned)(ef * LL + (r & 15)), __float_as_uint(vals[k]));
}
__global__ void k_fill_pool(const int* __restrict__ rows, const int* __restrict__ cols,
                            const float* __restrict__ vals, int* __restrict__ cur,
                            uint2* __restrict__ ent) {
    int k = blockIdx.x * blockDim.x + threadIdx.x;
    if (k >= DDIM) return;
    int pos = atomicAdd(&cur[rows[k]], 1);
    ent[pos] = make_uint2((unsigned)cols[k], __float_as_uint(vals[k]));
}

// ============================ per-layer kernels =============================
__global__ void k_init_h(const int* __restrict__ node_feat,
                         const float* __restrict__ atom_emb,
                         float* __restrict__ h) {
    int t = blockIdx.x * blockDim.x + threadIdx.x;
    if (t >= NN * HID) return;
    int n = t >> 6, c = t & 63;
    h[t] = atom_emb[node_feat[n] * HID + c];
}

// wtB[(a*64+c)*64 + b] = bf16(w_i[(b*64+c)*16 + a])   — B operand, [N][k]
__global__ void k_prep_wtB(const float* __restrict__ w_i, unsigned short* __restrict__ wtB) {
    int t = blockIdx.x * blockDim.x + threadIdx.x;
    if (t >= LL * HID * HID) return;
    int b = t & 63, N = t >> 6;
    int a = N >> 6, c = N & 63;
    wtB[t] = f2bf(w_i[(b * HID + c) * LL + a]);
}

__global__ void k_transpose_d1w(const float* __restrict__ d1w, float* __restrict__ d1wT) {
    int t = blockIdx.x * blockDim.x + threadIdx.x;
    if (t >= 128 * HID) return;
    int c = t & 63, j = t >> 6;
    d1wT[t] = d1w[c * 128 + j];
}

// ge[(ty*16+a)*64+c] = sum_b bond_emb_i[ty*64+b] * wtB[(a*64+c)*64+b]
__global__ void k_ge(const float* __restrict__ bond_emb_i,
                     const unsigned short* __restrict__ wtB, float* __restrict__ ge) {
    int t = blockIdx.x * blockDim.x + threadIdx.x;
    if (t >= 4 * LL * HID) return;
    int c = t & 63, a = (t >> 6) & 15, ty = t >> 10;
    float s = 0.f;
    for (int b = 0; b < HID; ++b)
        s += bond_emb_i[ty * HID + b] * bf2f(wtB[((a * HID + c) * HID) + b]);
    ge[t] = s;
}

// MFMA GEMM: g[node][N] = sum_b h[node][b] * wtB[N][b],  M=NN, N=1024, K=64
// wave handles 16 nodes x all 64 N-tiles; 2 x mfma_f32_16x16x32_bf16 per tile
__global__ void __launch_bounds__(256) k_gemm_g_mfma(
        const float* __restrict__ h,
        const unsigned short* __restrict__ wtB,
        unsigned short* __restrict__ g) {
    int wave = threadIdx.x >> 6;
    int lane = threadIdx.x & 63;
    int mgrp = blockIdx.x * 4 + wave;          // 16-node group
    if (mgrp >= NN / 16) return;               // 3125 groups, exact
    int mrow = lane & 15;
    int kgrp = lane >> 4;                      // 0..3
    // ---- A fragments: node = mgrp*16 + mrow, k = kgrp*8 + j (+32 for a1)
    const float* hrow = h + ((size_t)mgrp * 16 + mrow) * HID;
    float4 f0 = *(const float4*)(hrow + kgrp * 8);
    float4 f1 = *(const float4*)(hrow + kgrp * 8 + 4);
    float4 f2 = *(const float4*)(hrow + 32 + kgrp * 8);
    float4 f3 = *(const float4*)(hrow + 32 + kgrp * 8 + 4);
    bf16x8 a0, a1;
    a0[0] = (short)f2bf(f0.x); a0[1] = (short)f2bf(f0.y);
    a0[2] = (short)f2bf(f0.z); a0[3] = (short)f2bf(f0.w);
    a0[4] = (short)f2bf(f1.x); a0[5] = (short)f2bf(f1.y);
    a0[6] = (short)f2bf(f1.z); a0[7] = (short)f2bf(f1.w);
    a1[0] = (short)f2bf(f2.x); a1[1] = (short)f2bf(f2.y);
    a1[2] = (short)f2bf(f2.z); a1[3] = (short)f2bf(f2.w);
    a1[4] = (short)f2bf(f3.x); a1[5] = (short)f2bf(f3.y);
    a1[6] = (short)f2bf(f3.z); a1[7] = (short)f2bf(f3.w);

    // ---- B pointer: N = ntile*16 + (lane&15), k = kgrp*8 (+32)
    const unsigned short* bp = wtB + ((size_t)mrow * HID) + kgrp * 8;
    unsigned short* gp = g + (size_t)mgrp * 16 * 1024 + mrow;   // + m*1024 + ntile*16

    for (int ntile = 0; ntile < 64; ++ntile) {
        bf16x8 b0 = *(const bf16x8*)(bp);
        bf16x8 b1 = *(const bf16x8*)(bp + 32);
        f32x4 acc = {0.f, 0.f, 0.f, 0.f};
        acc = __builtin_amdgcn_mfma_f32_16x16x32_bf16(a0, b0, acc, 0, 0, 0);
        acc = __builtin_amdgcn_mfma_f32_16x16x32_bf16(a1, b1, acc, 0, 0, 0);
        // D: row m = kgrp*4 + r, col n = lane&15  (verified layout)
        #pragma unroll
        for (int r = 0; r < 4; ++r)
            gp[(size_t)(kgrp * 4 + r) * 1024] = f2bf(acc[r]);
        bp += 16 * HID;   // next 16 N rows
        gp += 16;         // next 16 output cols
    }
}

// fused n2p-gather + e2p-gather + bias + relu: one wave per d, 4-way unrolled
__global__ void __launch_bounds__(256) k_gather_q(
        const int* __restrict__ n2p_start, const uint2* __restrict__ n2p_ent,
        const int* __restrict__ e2p_start, const uint2* __restrict__ e2p_ent,
        const unsigned short* __restrict__ g, const float* __restrict__ ge,
        const float* __restrict__ bias_i, float* __restrict__ qrelu) {
    int wid = (blockIdx.x * 256 + threadIdx.x) >> 6;
    if (wid >= DDIM) return;
    int c = threadIdx.x & 63;
    float acc0 = 0.f, acc1 = 0.f, acc2 = 0.f, acc3 = 0.f;
    int s0 = n2p_start[wid], s1 = n2p_start[wid + 1];
    int j = s0;
    for (; j + 3 < s1; j += 4) {
        uint2 e0 = n2p_ent[j],     e1 = n2p_ent[j + 1];
        uint2 e2 = n2p_ent[j + 2], e3 = n2p_ent[j + 3];
        acc0 += __uint_as_float(e0.y) * bf2f(g[(size_t)e0.x * HID + c]);
        acc1 += __uint_as_float(e1.y) * bf2f(g[(size_t)e1.x * HID + c]);
        acc2 += __uint_as_float(e2.y) * bf2f(g[(size_t)e2.x * HID + c]);
        acc3 += __uint_as_float(e3.y) * bf2f(g[(size_t)e3.x * HID + c]);
    }
    for (; j < s1; ++j) {
        uint2 e = n2p_ent[j];
        acc0 += __uint_as_float(e.y) * bf2f(g[(size_t)e.x * HID + c]);
    }
    s0 = e2p_start[wid]; s1 = e2p_start[wid + 1];
    j = s0;
    for (; j + 1 < s1; j += 2) {
        uint2 e0 = e2p_ent[j], e1 = e2p_ent[j + 1];
        acc1 += __uint_as_float(e0.y) * ge[e0.x * HID + c];
        acc2 += __uint_as_float(e1.y) * ge[e1.x * HID + c];
    }
    for (; j < s1; ++j) {
        uint2 e = e2p_ent[j];
        acc0 += __uint_as_float(e.y) * ge[e.x * HID + c];
    }
    float acc = (acc0 + acc1) + (acc2 + acc3) + bias_i[c];
    qrelu[(size_t)wid * HID + c] = fmaxf(acc, 0.f);
}

// fused pool-gather + degree gate: one wave per node
__global__ void __launch_bounds__(256) k_pool_gate(
        const int* __restrict__ pstart, const uint2* __restrict__ pent,
        const float* __restrict__ qrelu, const float* __restrict__ degs,
        const float* __restrict__ d0w, const float* __restrict__ d0b,
        const float* __restrict__ d1wT, const float* __restrict__ d1b,
        float* __restrict__ h) {
    int wid = (blockIdx.x * 256 + threadIdx.x) >> 6;
    if (wid >= NN) return;
    int c = threadIdx.x & 63;
    float acc0 = 0.f, acc1 = 0.f;
    int s0 = pstart[wid], s1 = pstart[wid + 1];
    int j = s0;
    for (; j + 1 < s1; j += 2) {
        uint2 e0 = pent[j], e1 = pent[j + 1];
        acc0 += __uint_as_float(e0.y) * qrelu[(size_t)e0.x * HID + c];
        acc1 += __uint_as_float(e1.y) * qrelu[(size_t)e1.x * HID + c];
    }
    for (; j < s1; ++j) {
        uint2 e = pent[j];
        acc0 += __uint_as_float(e.y) * qrelu[(size_t)e.x * HID + c];
    }
    float acc = acc0 + acc1;
    float deg = degs[wid];
    float rv0 = fmaxf(deg * d0w[c]      + d0b[c],      0.f);
    float rv1 = fmaxf(deg * d0w[64 + c] + d0b[64 + c], 0.f);
    float gf = d1b[c];
    #pragma unroll 8
    for (int j2 = 0; j2 < 64; ++j2) {
        float f0 = __shfl(rv0, j2, 64);
        float f1 = __shfl(rv1, j2, 64);
        gf += d1wT[j2 * HID + c] * f0 + d1wT[(64 + j2) * HID + c] * f1;
    }
    h[(size_t)wid * HID + c] = acc * gf;
}

// ============================== epilogue ====================================
__global__ void k_reduce(const float* __restrict__ h, float* __restrict__ acc) {
    __shared__ float lds[256];
    int tid = threadIdx.x;
    float s = 0.f;
    for (int idx = blockIdx.x * 256 + tid; idx < NN * HID; idx += gridDim.x * 256)
        s += h[idx];
    lds[tid] = s;
    __syncthreads();
    if (tid < 64) {
        s = lds[tid] + lds[tid + 64] + lds[tid + 128] + lds[tid + 192];
        atomicAdd(&acc[tid], s);
    }
}

__global__ void k_final(const float* __restrict__ acc, const float* __restrict__ fw,
                        const float* __restrict__ fb, float* __restrict__ out) {
    int lane = threadIdx.x;
    float v = acc[lane] * (1.0f / NN) * fw[lane];
    for (int off = 32; off; off >>= 1) v += __shfl_down(v, off, 64);
    if (lane == 0) out[0] = v + fb[0];
}

// ============================================================================
extern "C" void kernel_launch(void* const* d_in, const int* in_sizes, int n_in,
                              void* d_out, int out_size, void* d_ws, size_t ws_size,
                              hipStream_t stream) {
    const int*   node_feat = (const int*)d_in[0];
    const int*   edge_feat = (const int*)d_in[1];
    const float* degs      = (const float*)d_in[2];
    const int*   n2p_rows  = (const int*)d_in[3];
    const int*   n2p_cols  = (const int*)d_in[4];
    const float* n2p_vals  = (const float*)d_in[5];
    const int*   e2p_rows  = (const int*)d_in[6];
    const int*   e2p_cols  = (const int*)d_in[7];
    const float* e2p_vals  = (const float*)d_in[8];
    const int*   pool_rows = (const int*)d_in[9];
    const int*   pool_cols = (const int*)d_in[10];
    const float* pool_vals = (const float*)d_in[11];
    const float* atom_emb  = (const float*)d_in[13];
    const float* bond_emb  = (const float*)d_in[14];
    const float* weights   = (const float*)d_in[15];
    const float* bias      = (const float*)d_in[16];
    const float* deg0_w    = (const float*)d_in[17];
    const float* deg0_b    = (const float*)d_in[18];
    const float* deg1_w    = (const float*)d_in[19];
    const float* deg1_b    = (const float*)d_in[20];
    const float* final_w   = (const float*)d_in[21];
    const float* final_b   = (const float*)d_in[22];
    float* out = (float*)d_out;

    char* wsb = (char*)d_ws;
    size_t off = 0;
    auto alloc = [&](size_t bytes) -> void* {
        void* ptr = wsb + off;
        off += (bytes + 255) & ~(size_t)255;
        return ptr;
    };
    float*          h       = (float*)alloc((size_t)NN * HID * 4);
    unsigned short* g       = (unsigned short*)alloc((size_t)NN * LL * HID * 2);
    float*          qrelu   = (float*)alloc((size_t)DDIM * HID * 4);
    unsigned short* wtB     = (unsigned short*)alloc((size_t)LL * HID * HID * 2);
    float*          ge      = (float*)alloc((size_t)4 * LL * HID * 4);
    float*          d1wT    = (float*)alloc((size_t)128 * HID * 4);
    float*          acc     = (float*)alloc(64 * 4);
    int*   n2p_start = (int*)alloc((size_t)(DDIM + 1) * 4);
    int*   e2p_start = (int*)alloc((size_t)(DDIM + 1) * 4);
    int*   pool_start= (int*)alloc((size_t)(NN + 1) * 4);
    int*   cursor    = (int*)alloc((size_t)(DDIM + 1) * 4);
    int*   partial   = (int*)alloc(512 * 4);
    uint2* n2p_ent   = (uint2*)alloc((size_t)PRR * 8);
    uint2* e2p_ent   = (uint2*)alloc((size_t)(PRR / 2) * 8);
    uint2* pool_ent  = (uint2*)alloc((size_t)DDIM * 8);

    // ---------------- CSR build (shared across layers) ----------------------
    k_zero_i<<<(DDIM + 255) / 256, 256, 0, stream>>>(n2p_start, DDIM);
    k_hist<<<(PRR + 255) / 256, 256, 0, stream>>>(n2p_rows, PRR, 4, n2p_start);
    k_scan_block<<<(DDIM + 1023) / 1024, 256, 0, stream>>>(n2p_start, cursor, partial, DDIM);
    k_scan_partial<<<1, 64, 0, stream>>>(partial, (DDIM + 1023) / 1024);
    k_scan_add<<<(DDIM + 255) / 256, 256, 0, stream>>>(cursor, partial, DDIM);
    k_copy_i<<<(DDIM + 255) / 256, 256, 0, stream>>>(cursor, n2p_start, DDIM);
    k_set_int<<<1, 1, 0, stream>>>(n2p_start + DDIM, PRR);
    k_fill_n2p<<<(PRR + 255) / 256, 256, 0, stream>>>(n2p_rows, n2p_cols, n2p_vals, cursor, n2p_ent);

    k_zero_i<<<(DDIM + 255) / 256, 256, 0, stream>>>(e2p_start, DDIM);
    k_hist<<<(PRR / 2 + 255) / 256, 256, 0, stream>>>(e2p_rows, PRR / 2, 4, e2p_start);
    k_scan_block<<<(DDIM + 1023) / 1024, 256, 0, stream>>>(e2p_start, cursor, partial, DDIM);
    k_scan_partial<<<1, 64, 0, stream>>>(partial, (DDIM + 1023) / 1024);
    k_scan_add<<<(DDIM + 255) / 256, 256, 0, stream>>>(cursor, partial, DDIM);
    k_copy_i<<<(DDIM + 255) / 256, 256, 0, stream>>>(cursor, e2p_start, DDIM);
    k_set_int<<<1, 1, 0, stream>>>(e2p_start + DDIM, PRR / 2);
    k_fill_e2p<<<(PRR / 2 + 255) / 256, 256, 0, stream>>>(e2p_rows, e2p_cols, e2p_vals,
                                                          edge_feat, cursor, e2p_ent);

    k_zero_i<<<(NN + 255) / 256, 256, 0, stream>>>(pool_start, NN);
    k_hist<<<(DDIM + 255) / 256, 256, 0, stream>>>(pool_rows, DDIM, 0, pool_start);
    k_scan_block<<<(NN + 1023) / 1024, 256, 0, stream>>>(pool_start, cursor, partial, NN);
    k_scan_partial<<<1, 64, 0, stream>>>(partial, (NN + 1023) / 1024);
    k_scan_add<<<(NN + 255) / 256, 256, 0, stream>>>(cursor, partial, NN);
    k_copy_i<<<(NN + 255) / 256, 256, 0, stream>>>(cursor, pool_start, NN);
    k_set_int<<<1, 1, 0, stream>>>(pool_start + NN, DDIM);
    k_fill_pool<<<(DDIM + 255) / 256, 256, 0, stream>>>(pool_rows, pool_cols, pool_vals,
                                                        cursor, pool_ent);

    // ---------------- layers ------------------------------------------------
    k_init_h<<<(NN * HID + 255) / 256, 256, 0, stream>>>(node_feat, atom_emb, h);

    for (int i = 0; i < NLAYERS; ++i) {
        const float* w_i = weights + (size_t)i * HID * HID * LL;
        k_prep_wtB<<<(LL * HID * HID) / 256, 256, 0, stream>>>(w_i, wtB);
        k_ge<<<(4 * LL * HID) / 256, 256, 0, stream>>>(bond_emb + i * 4 * HID, wtB, ge);
        k_transpose_d1w<<<(128 * HID) / 256, 256, 0, stream>>>(deg1_w + (size_t)i * HID * 128, d1wT);
        k_gemm_g_mfma<<<(NN / 16 + 3) / 4, 256, 0, stream>>>(h, wtB, g);
        k_gather_q<<<(DDIM * HID) / 256, 256, 0, stream>>>(n2p_start, n2p_ent,
                                                           e2p_start, e2p_ent,
                                                           g, ge, bias + i * HID, qrelu);
        k_pool_gate<<<(NN * HID + 255) / 256, 256, 0, stream>>>(pool_start, pool_ent,
                                                                qrelu, degs,
                                                                deg0_w + i * 2 * HID,
                                                                deg0_b + i * 2 * HID,
                                                                d1wT,
                                                                deg1_b + i * HID, h);
    }

    k_zero_i<<<1, 64, 0, stream>>>((int*)acc, 64);
    k_reduce<<<256, 256, 0, stream>>>(h, acc);
    k_final<<<1, 64, 0, stream>>>(acc, final_w, final_b, out);
}

// Round 5
// 1040.423 us; speedup vs baseline: 3.6043x; 1.3493x over previous
//
#include <hip/hip_runtime.h>

#define HID 64
#define LL 16
#define NLAYERS 4
#define NN 50000
#define NE 200000
#define PRR 1600000
#define DDIM 100000        // PRR / LL
#define MGRPS 3125         // NN / 16
#define GE_BASE 800000     // ge rows appended to g after NN*16 rows
#define GROWS 800064

typedef __attribute__((ext_vector_type(8))) short bf16x8;
typedef __attribute__((ext_vector_type(4))) float f32x4;

__device__ __forceinline__ unsigned short f2bf(float x) {
    unsigned u = __float_as_uint(x);
    unsigned r = (u + 0x7fffu + ((u >> 16) & 1u)) >> 16;
    return (unsigned short)r;
}
__device__ __forceinline__ float bf2f(unsigned short v) {
    return __uint_as_float((unsigned)v << 16);
}

// ======================= CSR build (once per call) ==========================
__global__ void k_zero_i(int* __restrict__ b, int n) {
    int t = blockIdx.x * blockDim.x + threadIdx.x;
    if (t < n) b[t] = 0;
}
__global__ void k_set_int(int* __restrict__ p, int v) { *p = v; }

// rank[k] = old count  (the hist atomic IS the rank assignment)
__global__ void k_hist_rank(const int* __restrict__ rows, int n, int shift,
                            int* __restrict__ cnt, int* __restrict__ rank) {
    int k = blockIdx.x * blockDim.x + threadIdx.x;
    if (k >= n) return;
    rank[k] = atomicAdd(&cnt[rows[k] >> shift], 1);
}

__global__ void __launch_bounds__(256) k_scan_block(const int* __restrict__ cnt,
                                                    int* __restrict__ excl,
                                                    int* __restrict__ partial, int B) {
    __shared__ int lds[1024];
    int tid = threadIdx.x;
    int base = blockIdx.x * 1024;
    int self[4];
    #pragma unroll
    for (int r = 0; r < 4; ++r) {
        int i = r * 256 + tid;
        self[r] = (base + i < B) ? cnt[base + i] : 0;
        lds[i] = self[r];
    }
    __syncthreads();
    for (int off = 1; off < 1024; off <<= 1) {
        int v[4];
        #pragma unroll
        for (int r = 0; r < 4; ++r) {
            int i = r * 256 + tid;
            v[r] = (i >= off) ? lds[i - off] : 0;
        }
        __syncthreads();
        #pragma unroll
        for (int r = 0; r < 4; ++r) lds[r * 256 + tid] += v[r];
        __syncthreads();
    }
    #pragma unroll
    for (int r = 0; r < 4; ++r) {
        int i = r * 256 + tid;
        if (base + i < B) excl[base + i] = lds[i] - self[r];
    }
    if (tid == 0) partial[blockIdx.x] = lds[1023];
}

__global__ void k_scan_partial(int* __restrict__ partial, int nb) {
    if (threadIdx.x == 0) {
        int run = 0;
        for (int i = 0; i < nb; ++i) { int v = partial[i]; partial[i] = run; run += v; }
    }
}

__global__ void k_scan_add(int* __restrict__ excl, const int* __restrict__ partial, int B) {
    int i = blockIdx.x * blockDim.x + threadIdx.x;
    if (i < B) excl[i] += partial[i >> 10];
}

// ent = (g_row_index, val_bits), atomic-free placement via start+rank
__global__ void k_fill_n2p(const int* __restrict__ rows, const int* __restrict__ cols,
                           const float* __restrict__ vals, const int* __restrict__ qstart,
                           const int* __restrict__ rank, uint2* __restrict__ ent) {
    int k = blockIdx.x * blockDim.x + threadIdx.x;
    if (k >= PRR) return;
    int r = rows[k];
    int pos = qstart[r >> 4] + rank[k];
    ent[pos] = make_uint2((unsigned)cols[k] * 16u + (unsigned)(r & 15),
                          __float_as_uint(vals[k]));
}
__global__ void k_fill_e2p(const int* __restrict__ rows, const int* __restrict__ cols,
                           const float* __restrict__ vals, const int* __restrict__ ef_arr,
                           const int* __restrict__ qstart, const int* __restrict__ rank,
                           uint2* __restrict__ ent) {
    int k = blockIdx.x * blockDim.x + threadIdx.x;
    if (k >= PRR / 2) return;
    int r = rows[k];
    unsigned ef = (unsigned)ef_arr[cols[k]];
    int pos = qstart[r >> 4] + rank[k];
    ent[pos] = make_uint2((unsigned)GE_BASE + ef * 16u + (unsigned)(r & 15),
                          __float_as_uint(vals[k]));
}
__global__ void k_fill_pool(const int* __restrict__ rows, const int* __restrict__ cols,
                            const float* __restrict__ vals, const int* __restrict__ pstart,
                            const int* __restrict__ rank, uint2* __restrict__ ent) {
    int k = blockIdx.x * blockDim.x + threadIdx.x;
    if (k >= DDIM) return;
    int pos = pstart[rows[k]] + rank[k];
    ent[pos] = make_uint2((unsigned)cols[k], __float_as_uint(vals[k]));
}

// ============================ per-layer kernels =============================
__global__ void k_init_h(const int* __restrict__ node_feat,
                         const float* __restrict__ atom_emb,
                         float* __restrict__ h) {
    int t = blockIdx.x * blockDim.x + threadIdx.x;
    if (t >= NN * HID) return;
    int n = t >> 6, c = t & 63;
    h[t] = atom_emb[node_feat[n] * HID + c];
}

// fused prep: wtB pack + d1wT transpose + ge (direct from w_i) into g tail rows
__global__ void k_prep(const float* __restrict__ w_i,
                       const float* __restrict__ bond_emb_i,
                       const float* __restrict__ d1w,
                       unsigned short* __restrict__ wtB,
                       float* __restrict__ d1wT,
                       unsigned short* __restrict__ g) {
    int t = blockIdx.x * blockDim.x + threadIdx.x;
    if (t < LL * HID * HID) {
        // wtB[(a*64+c)*64 + b] = bf16(w_i[(b*64+c)*16 + a])
        int b = t & 63, N = t >> 6;
        int a = N >> 6, c = N & 63;
        wtB[t] = f2bf(w_i[(b * HID + c) * LL + a]);
    } else if (t < LL * HID * HID + 128 * HID) {
        int u = t - LL * HID * HID;
        int c = u & 63, j = u >> 6;
        d1wT[u] = d1w[c * 128 + j];
    } else if (t < LL * HID * HID + 128 * HID + 4 * LL * HID) {
        int u = t - LL * HID * HID - 128 * HID;
        int c = u & 63, a = (u >> 6) & 15, ty = u >> 10;
        float s = 0.f;
        for (int b = 0; b < HID; ++b)
            s += bond_emb_i[ty * HID + b] * w_i[(b * HID + c) * LL + a];
        g[(size_t)(GE_BASE + ty * LL + a) * HID + c] = f2bf(s);
    }
}

// MFMA GEMM with 4-way M-group B-reuse: g[node][a*64+c] = sum_b h[node][b]*wtB[N][b]
__global__ void __launch_bounds__(256) k_gemm_g_mfma(
        const float* __restrict__ h,
        const unsigned short* __restrict__ wtB,
        unsigned short* __restrict__ g) {
    int wave = threadIdx.x >> 6;
    int lane = threadIdx.x & 63;
    int mg4 = blockIdx.x * 4 + wave;           // handles mgrps mg4*4 .. mg4*4+3
    if (mg4 * 4 >= MGRPS) return;
    int mrow = lane & 15;
    int kgrp = lane >> 4;

    bf16x8 A0[4], A1[4];
    bool valid[4];
    #pragma unroll
    for (int i = 0; i < 4; ++i) {
        int mgrp = mg4 * 4 + i;
        valid[i] = (mgrp < MGRPS);
        if (valid[i]) {
            const float* hrow = h + ((size_t)mgrp * 16 + mrow) * HID;
            float4 f0 = *(const float4*)(hrow + kgrp * 8);
            float4 f1 = *(const float4*)(hrow + kgrp * 8 + 4);
            float4 f2 = *(const float4*)(hrow + 32 + kgrp * 8);
            float4 f3 = *(const float4*)(hrow + 32 + kgrp * 8 + 4);
            bf16x8 a0, a1;
            a0[0] = (short)f2bf(f0.x); a0[1] = (short)f2bf(f0.y);
            a0[2] = (short)f2bf(f0.z); a0[3] = (short)f2bf(f0.w);
            a0[4] = (short)f2bf(f1.x); a0[5] = (short)f2bf(f1.y);
            a0[6] = (short)f2bf(f1.z); a0[7] = (short)f2bf(f1.w);
            a1[0] = (short)f2bf(f2.x); a1[1] = (short)f2bf(f2.y);
            a1[2] = (short)f2bf(f2.z); a1[3] = (short)f2bf(f2.w);
            a1[4] = (short)f2bf(f3.x); a1[5] = (short)f2bf(f3.y);
            a1[6] = (short)f2bf(f3.z); a1[7] = (short)f2bf(f3.w);
            A0[i] = a0; A1[i] = a1;
        } else {
            bf16x8 z;
            #pragma unroll
            for (int tt = 0; tt < 8; ++tt) z[tt] = 0;
            A0[i] = z; A1[i] = z;
        }
    }

    const unsigned short* bp = wtB + (size_t)mrow * HID + kgrp * 8;
    unsigned short* gp[4];
    #pragma unroll
    for (int i = 0; i < 4; ++i)
        gp[i] = g + (size_t)((mg4 * 4 + i) * 16 + kgrp * 4) * 1024 + mrow;

    for (int ntile = 0; ntile < 64; ++ntile) {
        bf16x8 b0 = *(const bf16x8*)(bp);
        bf16x8 b1 = *(const bf16x8*)(bp + 32);
        #pragma unroll
        for (int i = 0; i < 4; ++i) {
            if (!valid[i]) continue;
            f32x4 acc = {0.f, 0.f, 0.f, 0.f};
            acc = __builtin_amdgcn_mfma_f32_16x16x32_bf16(A0[i], b0, acc, 0, 0, 0);
            acc = __builtin_amdgcn_mfma_f32_16x16x32_bf16(A1[i], b1, acc, 0, 0, 0);
            #pragma unroll
            for (int r = 0; r < 4; ++r)
                gp[i][(size_t)r * 1024 + ntile * 16] = f2bf(acc[r]);
        }
        bp += 16 * HID;
    }
}

// unified gather (n2p + e2p via g-row payload) + bias + relu: one wave per d
__global__ void __launch_bounds__(256) k_gather_q(
        const int* __restrict__ qstart, const uint2* __restrict__ ent,
        const unsigned short* __restrict__ g,
        const float* __restrict__ bias_i, float* __restrict__ qrelu) {
    int wid = (blockIdx.x * 256 + threadIdx.x) >> 6;
    if (wid >= DDIM) return;
    int c = threadIdx.x & 63;
    float a0 = 0.f, a1 = 0.f, a2 = 0.f, a3 = 0.f;
    float a4 = 0.f, a5 = 0.f, a6 = 0.f, a7 = 0.f;
    int j = qstart[wid], e = qstart[wid + 1];
    for (; j + 7 < e; j += 8) {
        uint2 e0 = ent[j],     e1 = ent[j + 1], e2 = ent[j + 2], e3 = ent[j + 3];
        uint2 e4 = ent[j + 4], e5 = ent[j + 5], e6 = ent[j + 6], e7 = ent[j + 7];
        a0 += __uint_as_float(e0.y) * bf2f(g[(size_t)e0.x * HID + c]);
        a1 += __uint_as_float(e1.y) * bf2f(g[(size_t)e1.x * HID + c]);
        a2 += __uint_as_float(e2.y) * bf2f(g[(size_t)e2.x * HID + c]);
        a3 += __uint_as_float(e3.y) * bf2f(g[(size_t)e3.x * HID + c]);
        a4 += __uint_as_float(e4.y) * bf2f(g[(size_t)e4.x * HID + c]);
        a5 += __uint_as_float(e5.y) * bf2f(g[(size_t)e5.x * HID + c]);
        a6 += __uint_as_float(e6.y) * bf2f(g[(size_t)e6.x * HID + c]);
        a7 += __uint_as_float(e7.y) * bf2f(g[(size_t)e7.x * HID + c]);
    }
    for (; j + 1 < e; j += 2) {
        uint2 e0 = ent[j], e1 = ent[j + 1];
        a0 += __uint_as_float(e0.y) * bf2f(g[(size_t)e0.x * HID + c]);
        a1 += __uint_as_float(e1.y) * bf2f(g[(size_t)e1.x * HID + c]);
    }
    if (j < e) {
        uint2 e0 = ent[j];
        a2 += __uint_as_float(e0.y) * bf2f(g[(size_t)e0.x * HID + c]);
    }
    float s = ((a0 + a1) + (a2 + a3)) + ((a4 + a5) + (a6 + a7)) + bias_i[c];
    qrelu[(size_t)wid * HID + c] = fmaxf(s, 0.f);
}

// fused pool-gather + degree gate: one wave per node
__global__ void __launch_bounds__(256) k_pool_gate(
        const int* __restrict__ pstart, const uint2* __restrict__ pent,
        const float* __restrict__ qrelu, const float* __restrict__ degs,
        const float* __restrict__ d0w, const float* __restrict__ d0b,
        const float* __restrict__ d1wT, const float* __restrict__ d1b,
        float* __restrict__ h) {
    int wid = (blockIdx.x * 256 + threadIdx.x) >> 6;
    if (wid >= NN) return;
    int c = threadIdx.x & 63;
    float acc0 = 0.f, acc1 = 0.f;
    int j = pstart[wid], e = pstart[wid + 1];
    for (; j + 1 < e; j += 2) {
        uint2 e0 = pent[j], e1 = pent[j + 1];
        acc0 += __uint_as_float(e0.y) * qrelu[(size_t)e0.x * HID + c];
        acc1 += __uint_as_float(e1.y) * qrelu[(size_t)e1.x * HID + c];
    }
    if (j < e) {
        uint2 e0 = pent[j];
        acc0 += __uint_as_float(e0.y) * qrelu[(size_t)e0.x * HID + c];
    }
    float acc = acc0 + acc1;
    float deg = degs[wid];
    float rv0 = fmaxf(deg * d0w[c]      + d0b[c],      0.f);
    float rv1 = fmaxf(deg * d0w[64 + c] + d0b[64 + c], 0.f);
    float gf = d1b[c];
    #pragma unroll 8
    for (int j2 = 0; j2 < 64; ++j2) {
        float f0 = __shfl(rv0, j2, 64);
        float f1 = __shfl(rv1, j2, 64);
        gf += d1wT[j2 * HID + c] * f0 + d1wT[(64 + j2) * HID + c] * f1;
    }
    h[(size_t)wid * HID + c] = acc * gf;
}

// ============================== epilogue ====================================
__global__ void k_reduce(const float* __restrict__ h, float* __restrict__ acc) {
    __shared__ float lds[256];
    int tid = threadIdx.x;
    float s = 0.f;
    for (int idx = blockIdx.x * 256 + tid; idx < NN * HID; idx += gridDim.x * 256)
        s += h[idx];
    lds[tid] = s;
    __syncthreads();
    if (tid < 64) {
        s = lds[tid] + lds[tid + 64] + lds[tid + 128] + lds[tid + 192];
        atomicAdd(&acc[tid], s);
    }
}

__global__ void k_final(const float* __restrict__ acc, const float* __restrict__ fw,
                        const float* __restrict__ fb, float* __restrict__ out) {
    int lane = threadIdx.x;
    float v = acc[lane] * (1.0f / NN) * fw[lane];
    for (int off = 32; off; off >>= 1) v += __shfl_down(v, off, 64);
    if (lane == 0) out[0] = v + fb[0];
}

// ============================================================================
extern "C" void kernel_launch(void* const* d_in, const int* in_sizes, int n_in,
                              void* d_out, int out_size, void* d_ws, size_t ws_size,
                              hipStream_t stream) {
    const int*   node_feat = (const int*)d_in[0];
    const int*   edge_feat = (const int*)d_in[1];
    const float* degs      = (const float*)d_in[2];
    const int*   n2p_rows  = (const int*)d_in[3];
    const int*   n2p_cols  = (const int*)d_in[4];
    const float* n2p_vals  = (const float*)d_in[5];
    const int*   e2p_rows  = (const int*)d_in[6];
    const int*   e2p_cols  = (const int*)d_in[7];
    const float* e2p_vals  = (const float*)d_in[8];
    const int*   pool_rows = (const int*)d_in[9];
    const int*   pool_cols = (const int*)d_in[10];
    const float* pool_vals = (const float*)d_in[11];
    const float* atom_emb  = (const float*)d_in[13];
    const float* bond_emb  = (const float*)d_in[14];
    const float* weights   = (const float*)d_in[15];
    const float* bias      = (const float*)d_in[16];
    const float* deg0_w    = (const float*)d_in[17];
    const float* deg0_b    = (const float*)d_in[18];
    const float* deg1_w    = (const float*)d_in[19];
    const float* deg1_b    = (const float*)d_in[20];
    const float* final_w   = (const float*)d_in[21];
    const float* final_b   = (const float*)d_in[22];
    float* out = (float*)d_out;

    char* wsb = (char*)d_ws;
    size_t off = 0;
    auto alloc = [&](size_t bytes) -> void* {
        void* ptr = wsb + off;
        off += (bytes + 255) & ~(size_t)255;
        return ptr;
    };
    float*          h     = (float*)alloc((size_t)NN * HID * 4);              // 12.8 MB
    unsigned short* g     = (unsigned short*)alloc((size_t)GROWS * HID * 2);  // 102.4 MB
    float*          qrelu = (float*)alloc((size_t)DDIM * HID * 4);            // 25.6 MB (ranks scratch during CSR)
    unsigned short* wtB   = (unsigned short*)alloc((size_t)LL * HID * HID * 2);
    float*          d1wT  = (float*)alloc((size_t)128 * HID * 4);
    float*          acc   = (float*)alloc(64 * 4);
    int*   q_start   = (int*)alloc((size_t)(DDIM + 1) * 4);
    int*   pool_start= (int*)alloc((size_t)(NN + 1) * 4);
    int*   cnt       = (int*)alloc((size_t)(DDIM + 1) * 4);
    int*   partial   = (int*)alloc(512 * 4);
    uint2* ent       = (uint2*)alloc((size_t)(PRR + PRR / 2) * 8);            // 19.2 MB
    uint2* pool_ent  = (uint2*)alloc((size_t)DDIM * 8);

    // ranks live in qrelu (idle until layers start)
    int* n2p_rank  = (int*)qrelu;
    int* e2p_rank  = n2p_rank + PRR;
    int* pool_rank = e2p_rank + PRR / 2;

    // ---------------- CSR build (shared across layers) ----------------------
    k_zero_i<<<(DDIM + 255) / 256, 256, 0, stream>>>(cnt, DDIM);
    k_hist_rank<<<(PRR + 255) / 256, 256, 0, stream>>>(n2p_rows, PRR, 4, cnt, n2p_rank);
    k_hist_rank<<<(PRR / 2 + 255) / 256, 256, 0, stream>>>(e2p_rows, PRR / 2, 4, cnt, e2p_rank);
    k_scan_block<<<(DDIM + 1023) / 1024, 256, 0, stream>>>(cnt, q_start, partial, DDIM);
    k_scan_partial<<<1, 64, 0, stream>>>(partial, (DDIM + 1023) / 1024);
    k_scan_add<<<(DDIM + 255) / 256, 256, 0, stream>>>(q_start, partial, DDIM);
    k_set_int<<<1, 1, 0, stream>>>(q_start + DDIM, PRR + PRR / 2);
    k_fill_n2p<<<(PRR + 255) / 256, 256, 0, stream>>>(n2p_rows, n2p_cols, n2p_vals,
                                                      q_start, n2p_rank, ent);
    k_fill_e2p<<<(PRR / 2 + 255) / 256, 256, 0, stream>>>(e2p_rows, e2p_cols, e2p_vals,
                                                          edge_feat, q_start, e2p_rank, ent);

    k_zero_i<<<(NN + 255) / 256, 256, 0, stream>>>(cnt, NN);
    k_hist_rank<<<(DDIM + 255) / 256, 256, 0, stream>>>(pool_rows, DDIM, 0, cnt, pool_rank);
    k_scan_block<<<(NN + 1023) / 1024, 256, 0, stream>>>(cnt, pool_start, partial, NN);
    k_scan_partial<<<1, 64, 0, stream>>>(partial, (NN + 1023) / 1024);
    k_scan_add<<<(NN + 255) / 256, 256, 0, stream>>>(pool_start, partial, NN);
    k_set_int<<<1, 1, 0, stream>>>(pool_start + NN, DDIM);
    k_fill_pool<<<(DDIM + 255) / 256, 256, 0, stream>>>(pool_rows, pool_cols, pool_vals,
                                                        pool_start, pool_rank, pool_ent);

    // ---------------- layers ------------------------------------------------
    k_init_h<<<(NN * HID + 255) / 256, 256, 0, stream>>>(node_feat, atom_emb, h);

    for (int i = 0; i < NLAYERS; ++i) {
        const float* w_i = weights + (size_t)i * HID * HID * LL;
        int prep_threads = LL * HID * HID + 128 * HID + 4 * LL * HID;
        k_prep<<<(prep_threads + 255) / 256, 256, 0, stream>>>(
            w_i, bond_emb + i * 4 * HID, deg1_w + (size_t)i * HID * 128, wtB, d1wT, g);
        k_gemm_g_mfma<<<(MGRPS + 15) / 16, 256, 0, stream>>>(h, wtB, g);
        k_gather_q<<<(DDIM * HID) / 256, 256, 0, stream>>>(q_start, ent, g,
                                                           bias + i * HID, qrelu);
        k_pool_gate<<<(NN * HID + 255) / 256, 256, 0, stream>>>(pool_start, pool_ent,
                                                                qrelu, degs,
                                                                deg0_w + i * 2 * HID,
                                                                deg0_b + i * 2 * HID,
                                                                d1wT,
                                                                deg1_b + i * HID, h);
    }

    k_zero_i<<<1, 64, 0, stream>>>((int*)acc, 64);
    k_reduce<<<256, 256, 0, stream>>>(h, acc);
    k_final<<<1, 64, 0, stream>>>(acc, final_w, final_b, out);
}